// Round 11
// baseline (202.994 us; speedup 1.0000x reference)
//
#include <hip/hip_runtime.h>
#include <hip/hip_bf16.h>

#define L_    4096
#define DIN   512
#define DOUT  256
#define NH    4
#define HD    64
#define JW    128                      // L_/32 j-words per row

typedef unsigned short u16;
typedef __attribute__((ext_vector_type(8))) short short8;   // 8 x bf16
typedef __attribute__((ext_vector_type(4))) float floatx4;  // MFMA C/D frag

__device__ __forceinline__ u16 f2bf(float f) {  // RNE
  union { float f; unsigned u; } v; v.f = f;
  unsigned r = v.u + 0x7fff + ((v.u >> 16) & 1);
  return (u16)(r >> 16);
}
__device__ __forceinline__ unsigned cvt2(float a, float b) {  // HW pack fp32x2->bf16x2
  __hip_bfloat162 v = __float22bfloat162_rn(make_float2(a, b));
  return *reinterpret_cast<unsigned*>(&v);
}
__device__ __forceinline__ short8 pack8(const float* __restrict__ p) {
  float4 a = *(const float4*)p, b = *(const float4*)(p + 4);
  union { unsigned u[4]; short8 s; } r;
  r.u[0] = cvt2(a.x, a.y); r.u[1] = cvt2(a.z, a.w);
  r.u[2] = cvt2(b.x, b.y); r.u[3] = cvt2(b.z, b.w);
  return r.s;
}

// C/D map discovery (r10-verified contract); layout-map-free probes.
__device__ __forceinline__ void mfma_cdmap(int lane, int* rowm, int* colm) {
  const int c0 = lane & 15;
  union { u16 u[8]; short8 s; } a1, b1, a2, b2;
  const u16 one = f2bf(1.f), cid = f2bf((float)c0);
  #pragma unroll
  for (int j = 0; j < 8; ++j) { a1.u[j] = cid; b1.u[j] = one; a2.u[j] = one; b2.u[j] = cid; }
  floatx4 z = {0.f, 0.f, 0.f, 0.f};
  floatx4 dr = __builtin_amdgcn_mfma_f32_16x16x32_bf16(a1.s, b1.s, z, 0, 0, 0);
  floatx4 dc = __builtin_amdgcn_mfma_f32_16x16x32_bf16(a2.s, b2.s, z, 0, 0, 0);
  #pragma unroll
  for (int r = 0; r < 4; ++r) {
    rowm[r] = (int)(dr[r] * 0.03125f + 0.5f);
    colm[r] = (int)(dc[r] * 0.03125f + 0.5f);
  }
}

// ---------------------------------------------------------------------------
// MEGA kernel: grid 256 x 1024 (1 block/CU -> all co-resident; R7-validated
// assumption incl. cross-XCD release/acquire visibility).
//   Phase 1: waves 0-3 = k1 (h-stage -> MFMA with DIRECT pack8(W) fragments,
//            bit-identical to the k0b/Wf path) ; waves 4-15 = pack this
//            block's own 16 A-rows -> LDS bitmask (no global round-trip).
//            s1 -> LDS; WhTf + bd -> global ws.
//   Grid barrier: memset-zeroed [cnt,gen]; ACQ_REL add + ACQUIRE spin.
//   Phase 2: R3-verified k2 body verbatim (minus Abits prologue).
// LDS: phase structs overlaid via union (~53 KB); AbitL + s1L survive.
// ---------------------------------------------------------------------------
__global__ __launch_bounds__(1024) void mega(
    const float* __restrict__ h, const int* __restrict__ A,
    const float* __restrict__ W, const float* __restrict__ attn,
    const float* __restrict__ out_w, const float* __restrict__ out_b,
    float* __restrict__ out,
    u16* __restrict__ WhTf, float2* __restrict__ bdg, int* __restrict__ syncp)
{
  const int i0 = blockIdx.x * 16;
  const int t = threadIdx.x;
  const int wv = t >> 6, lane = t & 63, q = lane >> 4, c0 = lane & 15;

  union SMEM {
    struct {                            // phase 1 (k1)
      u16   hT[16][DIN + 8];
      float pAk1[16][DOUT + 8];
      float attnL[NH * 128];
      float s1p[4][64];
      float s2p[4][64];
    } p1;
    struct {                            // phase 2 (k2)
      float pA[NH][16][HD + 4];
      float pB[NH][16][HD + 4];
      float dden[NH][4][16];
      float rcpS[NH][16];
      u16  CnL[16][DOUT + 8];
    } p2;
  };
  __shared__ SMEM sm;
  __shared__ unsigned AbitL[16][JW + 2];   // survives phase switch
  __shared__ float s1L[64];                // survives phase switch

  int rowm[4], colm[4];
  mfma_cdmap(lane, rowm, colm);

  // ---- phase 1a: h-stage (waves 0-3) || A-pack -> AbitL (waves 4-15) ----
  if (t < 256) {
    sm.p1.attnL[t] = attn[t];
    sm.p1.attnL[t + 256] = attn[t + 256];
    #pragma unroll
    for (int rep = 0; rep < 4; ++rep) {
      const int idx = rep * 256 + t;
      const int row = idx >> 6, c8 = (idx & 63) * 8;
      const float* hp = h + (size_t)(i0 + row) * DIN + c8;
      float4 a = *(const float4*)hp;
      float4 b = *(const float4*)(hp + 4);
      union { unsigned u[4]; int4 v; } pk;
      pk.u[0] = cvt2(a.x, a.y); pk.u[1] = cvt2(a.z, a.w);
      pk.u[2] = cvt2(b.x, b.y); pk.u[3] = cvt2(b.z, b.w);
      *(int4*)&sm.p1.hT[row][c8] = pk.v;
    }
  } else {
    const int u = t - 256;               // 768 threads, 2048 bit-words
    #pragma unroll
    for (int rep = 0; rep < 3; ++rep) {
      const int w = u + rep * 768;
      if (w < 2048) {
        const int row = w >> 7, wI = w & 127;
        const int* p = A + (size_t)(i0 + row) * L_ + wI * 32;
        unsigned bits = 0u;
        #pragma unroll
        for (int wd = 0; wd < 8; ++wd) {
          int4 v = *(const int4*)(p + wd * 4);
          bits |= (v.x > 0 ? 1u : 0u) << (wd * 4 + 0);
          bits |= (v.y > 0 ? 1u : 0u) << (wd * 4 + 1);
          bits |= (v.z > 0 ? 1u : 0u) << (wd * 4 + 2);
          bits |= (v.w > 0 ? 1u : 0u) << (wd * 4 + 3);
        }
        AbitL[row][wI] = bits;
      }
    }
  }
  __syncthreads();

  // ---- phase 1b: k1 MFMA (waves 0-3), direct-W bf16 fragments ----
  if (t < 256) {
    const int cg = wv;                   // wave owns cols [cg*64, cg*64+64)
    floatx4 acc[4] = {};
    #pragma unroll
    for (int ks = 0; ks < 16; ++ks) {
      const int kb = ks * 32 + q * 8;
      short8 af = *(const short8*)&sm.p1.hT[c0][kb];
      #pragma unroll
      for (int nt = 0; nt < 4; ++nt) {
        const int col = cg * 64 + nt * 16 + c0;
        short8 bf = pack8(W + (size_t)col * DIN + kb);   // == Wf path values
        acc[nt] = __builtin_amdgcn_mfma_f32_16x16x32_bf16(af, bf, acc[nt], 0, 0, 0);
      }
    }
    #pragma unroll
    for (int nt = 0; nt < 4; ++nt)
      #pragma unroll
      for (int r = 0; r < 4; ++r)
        sm.p1.pAk1[rowm[r]][cg * 64 + nt * 16 + colm[r]] = acc[nt][r];
  }
  __syncthreads();

  if (t < 256) {  // s1/s2 partials: t = (qt, hh, r); 16 d's each
    const int r = t & 15, hh = (t >> 4) & 3, qt = t >> 6;
    float s1 = 0.f, s2 = 0.f;
    #pragma unroll
    for (int dd = 0; dd < 16; ++dd) {
      const int d = qt * 16 + dd;
      float v = sm.p1.pAk1[r][hh * 64 + d];
      s1 += v * sm.p1.attnL[hh * 128 + d];
      s2 += v * sm.p1.attnL[hh * 128 + 64 + d];
    }
    sm.p1.s1p[qt][hh * 16 + r] = s1;
    sm.p1.s2p[qt][hh * 16 + r] = s2;
  }
  __syncthreads();
  if (t < 64) {
    float s1 = sm.p1.s1p[0][t] + sm.p1.s1p[1][t] + sm.p1.s1p[2][t] + sm.p1.s1p[3][t];
    float s2 = sm.p1.s2p[0][t] + sm.p1.s2p[1][t] + sm.p1.s2p[2][t] + sm.p1.s2p[3][t];
    const int r = t & 15, hh = t >> 4;
    s1L[t] = s1;                                        // s1 stays in LDS
    bdg[hh * L_ + i0 + r] = make_float2(__expf(s2), __expf(0.2f * s2));
  }
  if (t < 256) {  // WhTf store (verified chunk layout)
    const int d = t;
    const int hd2 = d >> 6, nt = (d >> 4) & 3, dc0 = d & 15;
    const int jblock = i0 >> 5, qbase = (i0 & 31) >> 3;
    u16* base = WhTf + ((size_t)(hd2 * 4 + nt) * JW + jblock) * 512 + dc0 * 8;
    #pragma unroll
    for (int jh = 0; jh < 2; ++jh) {
      const int i = jh * 8;
      union { unsigned u[4]; int4 v; } pk;
      pk.u[0] = cvt2(sm.p1.pAk1[i + 0][d], sm.p1.pAk1[i + 1][d]);
      pk.u[1] = cvt2(sm.p1.pAk1[i + 2][d], sm.p1.pAk1[i + 3][d]);
      pk.u[2] = cvt2(sm.p1.pAk1[i + 4][d], sm.p1.pAk1[i + 5][d]);
      pk.u[3] = cvt2(sm.p1.pAk1[i + 6][d], sm.p1.pAk1[i + 7][d]);
      *(int4*)(base + (qbase + jh) * 128) = pk.v;
    }
  }

  // ---- grid barrier (single-use; syncp[0]=cnt, syncp[1]=gen, memset to 0) ----
  __syncthreads();                       // all block stores issued/drained
  if (t == 0) {
    int old = __hip_atomic_fetch_add(&syncp[0], 1, __ATOMIC_ACQ_REL,
                                     __HIP_MEMORY_SCOPE_AGENT);
    if (old == (int)gridDim.x - 1) {
      __hip_atomic_store(&syncp[1], 1, __ATOMIC_RELEASE,
                         __HIP_MEMORY_SCOPE_AGENT);
    } else {
      while (__hip_atomic_load(&syncp[1], __ATOMIC_ACQUIRE,
                               __HIP_MEMORY_SCOPE_AGENT) == 0)
        __builtin_amdgcn_s_sleep(2);
    }
  }
  __syncthreads();

  // ---- phase 2: k2 (R3-verified body; AbitL/s1L already in LDS) ----
  const int hd = wv & 3, jc = wv >> 2;
  const float s1v = s1L[hd * 16 + c0];
  const float av = __expf(s1v);          // exp(s1)
  const float cv = __expf(0.2f * s1v);   // exp(0.2*s1)
  const float th = __expf(-s1v);         // b >= th  <=>  s1+s2 >= 0
  const float2* bdh = bdg + (size_t)hd * L_;
  const u16* Wc = WhTf + (size_t)(hd * 4) * JW * 512 + (size_t)(jc * 32) * 512 + lane * 8;
  const int jbase = jc * 1024;

  floatx4 acc[4] = {};
  float dpart = 0.f;

  union PF { unsigned u[4]; short8 s; };

  auto issueV = [&](int kt, float4* v) {
    const float2* p = bdh + jbase + kt * 32 + q * 8;
    v[0] = *(const float4*)p;       v[1] = *(const float4*)(p + 2);
    v[2] = *(const float4*)(p + 4); v[3] = *(const float4*)(p + 6);
  };
  auto issueW = [&](int kt, short8* w) {
    #pragma unroll
    for (int nt = 0; nt < 4; ++nt)
      w[nt] = *(const short8*)(Wc + ((size_t)nt * JW + kt) * 512);
  };
  auto sm8 = [&](const float4* v, int kt, PF& pf) {  // softmax -> bf16 A-frag
    const unsigned mb = (AbitL[c0][jc * 32 + kt] >> (q * 8)) & 0xffu;
    const float bb[8] = {v[0].x, v[0].z, v[1].x, v[1].z, v[2].x, v[2].z, v[3].x, v[3].z};
    const float dd[8] = {v[0].y, v[0].w, v[1].y, v[1].w, v[2].y, v[2].w, v[3].y, v[3].w};
    float ex[8];
    #pragma unroll
    for (int jj = 0; jj < 8; ++jj) {
      float p = (bb[jj] >= th) ? (av * bb[jj]) : (cv * dd[jj]);
      ex[jj] = ((mb >> jj) & 1u) ? p : 0.f;
      dpart += ex[jj];
    }
    pf.u[0] = cvt2(ex[0], ex[1]); pf.u[1] = cvt2(ex[2], ex[3]);
    pf.u[2] = cvt2(ex[4], ex[5]); pf.u[3] = cvt2(ex[6], ex[7]);
  };
  auto mfma4 = [&](PF& pf, const short8* w) {
    #pragma unroll
    for (int nt = 0; nt < 4; ++nt)
      acc[nt] = __builtin_amdgcn_mfma_f32_16x16x32_bf16(pf.s, w[nt], acc[nt], 0, 0, 0);
  };

  float4 vA[4], vB[4];
  short8 wA[4], wB[4];
  PF pfA, pfB;

  issueV(0, vA); issueW(0, wA);
  issueV(1, vB); issueW(1, wB);
  __builtin_amdgcn_sched_barrier(0);
  sm8(vA, 0, pfA);

  #pragma unroll 1
  for (int u2 = 0; u2 < 15; ++u2) {
    const int kt = 2 * u2;
    issueV(kt + 2, vA);
    __builtin_amdgcn_sched_barrier(0);
    sm8(vB, kt + 1, pfB);
    mfma4(pfA, wA);
    __builtin_amdgcn_sched_barrier(0);
    issueW(kt + 2, wA);
    issueV(kt + 3, vB);
    __builtin_amdgcn_sched_barrier(0);
    mfma4(pfB, wB);
    __builtin_amdgcn_sched_barrier(0);
    issueW(kt + 3, wB);
    sm8(vA, kt + 2, pfA);
    __builtin_amdgcn_sched_barrier(0);
  }
  mfma4(pfA, wA);
  sm8(vB, 31, pfB);
  mfma4(pfB, wB);

  dpart += __shfl_xor(dpart, 16, 64);
  dpart += __shfl_xor(dpart, 32, 64);
  if (lane < 16) sm.p2.dden[hd][jc][lane] = dpart;

  auto writeT = [&](float (*P)[HD + 4]) {
    #pragma unroll
    for (int nt = 0; nt < 4; ++nt)
      #pragma unroll
      for (int r = 0; r < 4; ++r)
        P[rowm[r]][nt * 16 + colm[r]] = acc[nt][r];
  };
  auto addB2A = [&]() {
    const int h2 = t >> 8, rem = t & 255, row = rem >> 4, d4 = (rem & 15) * 4;
    float4* a = (float4*)&sm.p2.pA[h2][row][d4];
    float4 bv = *(float4*)&sm.p2.pB[h2][row][d4];
    float4 av2 = *a;
    av2.x += bv.x; av2.y += bv.y; av2.z += bv.z; av2.w += bv.w;
    *a = av2;
  };

  if (jc == 0) writeT(sm.p2.pA[hd]);
  if (jc == 1) writeT(sm.p2.pB[hd]);
  __syncthreads();
  if (t < 64) {
    const int hh = t >> 4, r = t & 15;
    float den = sm.p2.dden[hh][0][r] + sm.p2.dden[hh][1][r]
              + sm.p2.dden[hh][2][r] + sm.p2.dden[hh][3][r];
    sm.p2.rcpS[hh][r] = (den > 0.f) ? (1.f / den) : 0.f;
  }
  addB2A();
  __syncthreads();
  if (jc == 2) writeT(sm.p2.pB[hd]);
  __syncthreads();
  addB2A();
  __syncthreads();
  if (jc == 3) writeT(sm.p2.pB[hd]);
  __syncthreads();
  addB2A();
  __syncthreads();

  {  // Cn (bf16)
    const int row = t >> 6, c4 = (t & 63) * 4;
    #pragma unroll
    for (int x = 0; x < 4; ++x) {
      const int col = c4 + x;
      const int hh = col >> 6, d = col & 63;
      sm.p2.CnL[row][col] = f2bf(sm.p2.pA[hh][row][d] * sm.p2.rcpS[hh][row]);
    }
  }
  __syncthreads();

  if (wv < 4) {  // projection: Out2(16x256) = Cn @ out_w.T
    const int cg = wv;
    floatx4 o[4] = {};
    #pragma unroll
    for (int kt = 0; kt < DOUT / 32; ++kt) {
      const int kb2 = kt * 32 + q * 8;
      short8 afr = *(const short8*)(&sm.p2.CnL[c0][kb2]);
      #pragma unroll
      for (int nt = 0; nt < 4; ++nt) {
        const int col = cg * 64 + nt * 16 + c0;
        short8 bfo = pack8(out_w + (size_t)col * DOUT + kb2);
        o[nt] = __builtin_amdgcn_mfma_f32_16x16x32_bf16(afr, bfo, o[nt], 0, 0, 0);
      }
    }
    #pragma unroll
    for (int nt = 0; nt < 4; ++nt)
      #pragma unroll
      for (int r = 0; r < 4; ++r) {
        const int col = cg * 64 + nt * 16 + colm[r];
        out[(size_t)(i0 + rowm[r]) * DOUT + col] = o[nt][r] + out_b[col];
      }
  }
}

// ---------------------------------------------------------------------------
extern "C" void kernel_launch(void* const* d_in, const int* in_sizes, int n_in,
                              void* d_out, int out_size, void* d_ws, size_t ws_size,
                              hipStream_t stream) {
  const float* h     = (const float*)d_in[0];   // (4096, 512) fp32
  const int*   A     = (const int*)d_in[1];     // (4096, 4096) int32
  const float* W     = (const float*)d_in[2];   // (256, 512) fp32
  const float* attn  = (const float*)d_in[3];   // (4, 128) fp32
  const float* out_w = (const float*)d_in[4];   // (256, 256) fp32
  const float* out_b = (const float*)d_in[5];   // (256,) fp32
  float* outp = (float*)d_out;                  // (4096, 256) fp32

  // ws: WhTf bf16 (2 MB) | bd float2 (128 KB) | sync (2 ints)
  const size_t WHTF_B = (size_t)DOUT * L_ * 2;          // 2097152
  const size_t BD_B   = (size_t)NH * L_ * 8;            // 131072
  u16*    WhTf  = (u16*)d_ws;
  float2* bdg   = (float2*)((char*)d_ws + WHTF_B);
  int*    syncp = (int*)((char*)d_ws + WHTF_B + BD_B);

  hipMemsetAsync(syncp, 0, 2 * sizeof(int), stream);    // zero barrier state
  hipLaunchKernelGGL(mega, dim3(L_ / 16), dim3(1024), 0, stream,
                     h, A, W, attn, out_w, out_b, outp, WhTf, bdg, syncp);
}

// Round 12
// 155.059 us; speedup vs baseline: 1.3091x; 1.3091x over previous
//
#include <hip/hip_runtime.h>
#include <hip/hip_bf16.h>

#define L_    4096
#define DIN   512
#define DOUT  256
#define NH    4
#define HD    64
#define JW    128                      // L_/32 j-words per row

typedef unsigned short u16;
typedef __attribute__((ext_vector_type(8))) short short8;   // 8 x bf16
typedef __attribute__((ext_vector_type(4))) float floatx4;  // MFMA C/D frag

__device__ __forceinline__ u16 f2bf(float f) {  // RNE
  union { float f; unsigned u; } v; v.f = f;
  unsigned r = v.u + 0x7fff + ((v.u >> 16) & 1);
  return (u16)(r >> 16);
}
__device__ __forceinline__ unsigned cvt2(float a, float b) {  // HW pack fp32x2->bf16x2
  __hip_bfloat162 v = __float22bfloat162_rn(make_float2(a, b));
  return *reinterpret_cast<unsigned*>(&v);
}
__device__ __forceinline__ short8 pack8(const float* __restrict__ p) {
  float4 a = *(const float4*)p, b = *(const float4*)(p + 4);
  union { unsigned u[4]; short8 s; } r;
  r.u[0] = cvt2(a.x, a.y); r.u[1] = cvt2(a.z, a.w);
  r.u[2] = cvt2(b.x, b.y); r.u[3] = cvt2(b.z, b.w);
  return r.s;
}

// C/D map discovery (r10-verified contract); layout-map-free probes.
__device__ __forceinline__ void mfma_cdmap(int lane, int* rowm, int* colm) {
  const int c0 = lane & 15;
  union { u16 u[8]; short8 s; } a1, b1, a2, b2;
  const u16 one = f2bf(1.f), cid = f2bf((float)c0);
  #pragma unroll
  for (int j = 0; j < 8; ++j) { a1.u[j] = cid; b1.u[j] = one; a2.u[j] = one; b2.u[j] = cid; }
  floatx4 z = {0.f, 0.f, 0.f, 0.f};
  floatx4 dr = __builtin_amdgcn_mfma_f32_16x16x32_bf16(a1.s, b1.s, z, 0, 0, 0);
  floatx4 dc = __builtin_amdgcn_mfma_f32_16x16x32_bf16(a2.s, b2.s, z, 0, 0, 0);
  #pragma unroll
  for (int r = 0; r < 4; ++r) {
    rowm[r] = (int)(dr[r] * 0.03125f + 0.5f);
    colm[r] = (int)(dc[r] * 0.03125f + 0.5f);
  }
}

// ---------------------------------------------------------------------------
// k_ab: A (64 MB) -> Abits (2 MB bitmask)  [all 2048 blocks; coalesced]
//       + W -> Wf bf16 fragment pack       [blocks 0..15]   (R10-verified)
// ---------------------------------------------------------------------------
__global__ __launch_bounds__(256) void k_ab(const int* __restrict__ A,
                                            unsigned* __restrict__ Abits,
                                            const float* __restrict__ W,
                                            u16* __restrict__ Wf) {
  const int t = threadIdx.x;
  const int g = blockIdx.x * 256 + t;   // 524288 threads
  const int lane = t & 63;
  #pragma unroll
  for (int r = 0; r < 8; ++r) {
    const size_t gi = (size_t)r * 524288 + g;     // int4 index
    int4 v = *(const int4*)(A + gi * 4);
    unsigned nib = (v.x > 0 ? 1u : 0u) | (v.y > 0 ? 2u : 0u)
                 | (v.z > 0 ? 4u : 0u) | (v.w > 0 ? 8u : 0u);
    unsigned part = nib << ((lane & 7) * 4);
    part |= __shfl_xor(part, 1, 64);
    part |= __shfl_xor(part, 2, 64);
    part |= __shfl_xor(part, 4, 64);
    if ((lane & 7) == 0) Abits[gi >> 3] = part;
  }
  if (blockIdx.x < 16) {   // W pack
    const int col = g >> 4, kblock = g & 15;
    const int cg = col >> 6, nt = (col >> 4) & 3, c0 = col & 15;
    const float* src = W + (size_t)col * DIN + kblock * 32;
    u16* dst = Wf + ((size_t)(cg * 4 + nt) * 16 + kblock) * 512 + c0 * 8;
    #pragma unroll
    for (int q = 0; q < 4; ++q) {
      short8 v = pack8(src + q * 8);
      *(short8*)(dst + q * 128) = v;
    }
  }
}

// ---------------------------------------------------------------------------
// K1 (DECOMPOSED): grid 1024 = (tile, cg); 256 threads = 4 waves, wave = nt.
// Per-head stripe is self-contained: s_i[l][h] needs only Wh cols
// [h*64,h*64+64), and the WhTf chunk layout for hd=cg lives in the stripe.
// 4 blocks/CU co-resident (21 KB LDS, small VGPR) -> 16 independent waves/CU
// vs R10's 4. h-tile staged redundantly per cg (+24 MB HBM, ~4 us).
// Output contracts (Wf order, WhTf chunk order, s1, bd) bit-identical.
// ---------------------------------------------------------------------------
__global__ __launch_bounds__(256) void k1_wh(
    const float* __restrict__ h, const u16* __restrict__ Wf,
    const float* __restrict__ attn,
    u16* __restrict__ WhTf, float* __restrict__ s1g, float2* __restrict__ bdg)
{
  const int bid = blockIdx.x;           // 1024 blocks
  const int tile = bid >> 2, cg = bid & 3;
  const int i0 = tile * 16;
  const int t = threadIdx.x;            // 256 threads = 4 waves
  const int wv = t >> 6, lane = t & 63, q = lane >> 4, c0 = lane & 15;
  const int nt = wv;                    // wave owns cols [cg*64+nt*16, +16)
  int rowm[4], colm[4];
  mfma_cdmap(lane, rowm, colm);

  __shared__ u16  hT[16][DIN + 8];
  __shared__ float pS[16][HD + 4];      // 16 x 64 Wh stripe (head cg)

  #pragma unroll
  for (int rep = 0; rep < 4; ++rep) {   // stage h-tile coalesced (bf16)
    const int idx = rep * 256 + t;
    const int row = idx >> 6, c8 = (idx & 63) * 8;
    const float* hp = h + (size_t)(i0 + row) * DIN + c8;
    float4 a = *(const float4*)hp;
    float4 b = *(const float4*)(hp + 4);
    union { unsigned u[4]; int4 v; } pk;
    pk.u[0] = cvt2(a.x, a.y); pk.u[1] = cvt2(a.z, a.w);
    pk.u[2] = cvt2(b.x, b.y); pk.u[3] = cvt2(b.z, b.w);
    *(int4*)&hT[row][c8] = pk.v;
  }
  __syncthreads();

  floatx4 acc = {0.f, 0.f, 0.f, 0.f};
  #pragma unroll
  for (int ks = 0; ks < 16; ++ks) {     // full K=512, one nt per wave
    const int kb = ks * 32 + q * 8;
    short8 af = *(const short8*)&hT[c0][kb];
    short8 bf = *(const short8*)(Wf + ((size_t)(cg * 4 + nt) * 16 + ks) * 512 + lane * 8);
    acc = __builtin_amdgcn_mfma_f32_16x16x32_bf16(af, bf, acc, 0, 0, 0);
  }
  #pragma unroll
  for (int r = 0; r < 4; ++r)
    pS[rowm[r]][nt * 16 + colm[r]] = acc[r];
  __syncthreads();

  if (wv == 0) {   // s1/s2 for head cg: lane = qt*16 + r, 16-dim partials
    const int r = lane & 15, qt = lane >> 4;
    float s1 = 0.f, s2 = 0.f;
    #pragma unroll
    for (int dd = 0; dd < 16; ++dd) {
      const int d = qt * 16 + dd;
      float v = pS[r][d];
      s1 += v * attn[cg * 128 + d];
      s2 += v * attn[cg * 128 + 64 + d];
    }
    s1 += __shfl_xor(s1, 16, 64); s1 += __shfl_xor(s1, 32, 64);
    s2 += __shfl_xor(s2, 16, 64); s2 += __shfl_xor(s2, 32, 64);
    if (lane < 16) {
      s1g[cg * L_ + i0 + r] = s1;
      bdg[cg * L_ + i0 + r] = make_float2(__expf(s2), __expf(0.2f * s2));
    }
  }
  if (wv == 1) {   // WhTf stripe store: dl = t-64 in [0,64), global d = cg*64+dl
    const int dl = t - 64;
    const int nt2 = dl >> 4, dc0 = dl & 15;
    const int jblock = i0 >> 5, qbase = (i0 & 31) >> 3;
    u16* base = WhTf + ((size_t)(cg * 4 + nt2) * JW + jblock) * 512 + dc0 * 8;
    #pragma unroll
    for (int jh = 0; jh < 2; ++jh) {
      const int i = jh * 8;
      union { unsigned u[4]; int4 v; } pk;
      pk.u[0] = cvt2(pS[i + 0][dl], pS[i + 1][dl]);
      pk.u[1] = cvt2(pS[i + 2][dl], pS[i + 3][dl]);
      pk.u[2] = cvt2(pS[i + 4][dl], pS[i + 5][dl]);
      pk.u[3] = cvt2(pS[i + 6][dl], pS[i + 7][dl]);
      *(int4*)(base + (qbase + jh) * 128) = pk.v;
    }
  }
}

// ---------------------------------------------------------------------------
// K2: masked softmax + PV + fused projection (R10-verified 47.9 us variant,
// verbatim).
// ---------------------------------------------------------------------------
__global__ __launch_bounds__(1024) void k2_attn(
    const unsigned* __restrict__ Abits, const u16* __restrict__ WhTf,
    const float* __restrict__ s1g, const float2* __restrict__ bdg,
    const float* __restrict__ out_w, const float* __restrict__ out_b,
    float* __restrict__ out)
{
  const int i0 = blockIdx.x * 16;
  const int t = threadIdx.x;
  const int wv = t >> 6, lane = t & 63, q = lane >> 4, c0 = lane & 15;
  const int hd = wv & 3, jc = wv >> 2;

  __shared__ float pA[NH][16][HD + 4];
  __shared__ float pB[NH][16][HD + 4];
  __shared__ float dden[NH][4][16];
  __shared__ float rcpS[NH][16];
  __shared__ u16  CnL[16][DOUT + 8];
  __shared__ unsigned AbitL[16][JW + 2];   // row-stride 130 -> varied banks

  {  // prologue: stage this block's 16 rows of the bitmask (8 KB, coalesced)
    const int row = t >> 6, l = t & 63;
    uint2 w2 = *(const uint2*)&Abits[(size_t)(i0 + row) * JW + l * 2];
    AbitL[row][l * 2] = w2.x;
    AbitL[row][l * 2 + 1] = w2.y;
  }
  int rowm[4], colm[4];
  mfma_cdmap(lane, rowm, colm);
  __syncthreads();

  const float s1v = s1g[hd * L_ + i0 + c0];
  const float av = __expf(s1v);          // exp(s1)
  const float cv = __expf(0.2f * s1v);   // exp(0.2*s1)
  const float th = __expf(-s1v);         // b >= th  <=>  s1+s2 >= 0
  const float2* bdh = bdg + (size_t)hd * L_;
  const u16* Wc = WhTf + (size_t)(hd * 4) * JW * 512 + (size_t)(jc * 32) * 512 + lane * 8;
  const int jbase = jc * 1024;

  floatx4 acc[4] = {};
  float dpart = 0.f;

  union PF { unsigned u[4]; short8 s; };

  auto issueV = [&](int kt, float4* v) {
    const float2* p = bdh + jbase + kt * 32 + q * 8;
    v[0] = *(const float4*)p;       v[1] = *(const float4*)(p + 2);
    v[2] = *(const float4*)(p + 4); v[3] = *(const float4*)(p + 6);
  };
  auto issueW = [&](int kt, short8* w) {
    #pragma unroll
    for (int nt = 0; nt < 4; ++nt)
      w[nt] = *(const short8*)(Wc + ((size_t)nt * JW + kt) * 512);
  };
  auto sm8 = [&](const float4* v, int kt, PF& pf) {  // softmax -> bf16 A-frag
    const unsigned mb = (AbitL[c0][jc * 32 + kt] >> (q * 8)) & 0xffu;
    const float bb[8] = {v[0].x, v[0].z, v[1].x, v[1].z, v[2].x, v[2].z, v[3].x, v[3].z};
    const float dd[8] = {v[0].y, v[0].w, v[1].y, v[1].w, v[2].y, v[2].w, v[3].y, v[3].w};
    float ex[8];
    #pragma unroll
    for (int jj = 0; jj < 8; ++jj) {
      float p = (bb[jj] >= th) ? (av * bb[jj]) : (cv * dd[jj]);
      ex[jj] = ((mb >> jj) & 1u) ? p : 0.f;
      dpart += ex[jj];
    }
    pf.u[0] = cvt2(ex[0], ex[1]); pf.u[1] = cvt2(ex[2], ex[3]);
    pf.u[2] = cvt2(ex[4], ex[5]); pf.u[3] = cvt2(ex[6], ex[7]);
  };
  auto mfma4 = [&](PF& pf, const short8* w) {
    #pragma unroll
    for (int nt = 0; nt < 4; ++nt)
      acc[nt] = __builtin_amdgcn_mfma_f32_16x16x32_bf16(pf.s, w[nt], acc[nt], 0, 0, 0);
  };

  float4 vA[4], vB[4];
  short8 wA[4], wB[4];
  PF pfA, pfB;

  issueV(0, vA); issueW(0, wA);
  issueV(1, vB); issueW(1, wB);
  __builtin_amdgcn_sched_barrier(0);
  sm8(vA, 0, pfA);

  #pragma unroll 1
  for (int u = 0; u < 15; ++u) {
    const int kt = 2 * u;
    issueV(kt + 2, vA);                      // vA freed by sm8 last iter
    __builtin_amdgcn_sched_barrier(0);
    sm8(vB, kt + 1, pfB);                    // vB issued last iter (covered)
    mfma4(pfA, wA);                          // wA issued last iter (covered)
    __builtin_amdgcn_sched_barrier(0);
    issueW(kt + 2, wA);
    issueV(kt + 3, vB);
    __builtin_amdgcn_sched_barrier(0);
    mfma4(pfB, wB);                          // wB issued last iter (covered)
    __builtin_amdgcn_sched_barrier(0);
    issueW(kt + 3, wB);
    sm8(vA, kt + 2, pfA);                    // vA issued at loop top
    __builtin_amdgcn_sched_barrier(0);
  }
  mfma4(pfA, wA);
  sm8(vB, 31, pfB);
  mfma4(pfB, wB);

  dpart += __shfl_xor(dpart, 16, 64);
  dpart += __shfl_xor(dpart, 32, 64);
  if (lane < 16) dden[hd][jc][lane] = dpart;

  auto writeT = [&](float (*P)[HD + 4]) {
    #pragma unroll
    for (int nt = 0; nt < 4; ++nt)
      #pragma unroll
      for (int r = 0; r < 4; ++r)
        P[rowm[r]][nt * 16 + colm[r]] = acc[nt][r];
  };
  auto addB2A = [&]() {
    const int h2 = t >> 8, rem = t & 255, row = rem >> 4, d4 = (rem & 15) * 4;
    float4* a = (float4*)&pA[h2][row][d4];
    float4 bv = *(float4*)&pB[h2][row][d4];
    float4 av2 = *a;
    av2.x += bv.x; av2.y += bv.y; av2.z += bv.z; av2.w += bv.w;
    *a = av2;
  };

  if (jc == 0) writeT(pA[hd]);
  if (jc == 1) writeT(pB[hd]);
  __syncthreads();
  if (t < 64) {
    const int hh = t >> 4, r = t & 15;
    float den = dden[hh][0][r] + dden[hh][1][r] + dden[hh][2][r] + dden[hh][3][r];
    rcpS[hh][r] = (den > 0.f) ? (1.f / den) : 0.f;  // empty row -> out = bias
  }
  addB2A();
  __syncthreads();
  if (jc == 2) writeT(pB[hd]);
  __syncthreads();
  addB2A();
  __syncthreads();
  if (jc == 3) writeT(pB[hd]);
  __syncthreads();
  addB2A();
  __syncthreads();

  {  // Cn (bf16)
    const int row = t >> 6, c4 = (t & 63) * 4;
    #pragma unroll
    for (int x = 0; x < 4; ++x) {
      const int col = c4 + x;
      const int hh = col >> 6, d = col & 63;
      CnL[row][col] = f2bf(pA[hh][row][d] * rcpS[hh][row]);
    }
  }
  __syncthreads();

  if (wv < 4) {  // projection: Out2(16x256) = Cn @ out_w.T
    const int cg = wv;
    floatx4 o[4] = {};
    #pragma unroll
    for (int kt = 0; kt < DOUT / 32; ++kt) {
      const int kb2 = kt * 32 + q * 8;
      short8 afr = *(const short8*)(&CnL[c0][kb2]);
      #pragma unroll
      for (int nt = 0; nt < 4; ++nt) {
        const int col = cg * 64 + nt * 16 + c0;
        short8 bfo = pack8(out_w + (size_t)col * DOUT + kb2);
        o[nt] = __builtin_amdgcn_mfma_f32_16x16x32_bf16(afr, bfo, o[nt], 0, 0, 0);
      }
    }
    #pragma unroll
    for (int nt = 0; nt < 4; ++nt)
      #pragma unroll
      for (int r = 0; r < 4; ++r) {
        const int col = cg * 64 + nt * 16 + colm[r];
        out[(size_t)(i0 + rowm[r]) * DOUT + col] = o[nt][r] + out_b[col];
      }
  }
}

// ---------------------------------------------------------------------------
extern "C" void kernel_launch(void* const* d_in, const int* in_sizes, int n_in,
                              void* d_out, int out_size, void* d_ws, size_t ws_size,
                              hipStream_t stream) {
  const float* h     = (const float*)d_in[0];   // (4096, 512) fp32
  const int*   A     = (const int*)d_in[1];     // (4096, 4096) int32
  const float* W     = (const float*)d_in[2];   // (256, 512) fp32
  const float* attn  = (const float*)d_in[3];   // (4, 128) fp32
  const float* out_w = (const float*)d_in[4];   // (256, 256) fp32
  const float* out_b = (const float*)d_in[5];   // (256,) fp32
  float* outp = (float*)d_out;                  // (4096, 256) fp32

  // ws: WhTf bf16 (2 MB) | s1 f32 (64 KB) | bd float2 (128 KB) | Abits (2 MB)
  const size_t WHTF_B  = (size_t)DOUT * L_ * 2;          // 2097152
  const size_t S1_B    = (size_t)NH * L_ * 4;            // 65536
  const size_t BD_B    = (size_t)NH * L_ * 8;            // 131072
  const size_t ABITS_B = (size_t)L_ * JW * 4;            // 2097152
  const size_t AB_OFF  = WHTF_B + S1_B + BD_B;

  u16*    WhTf = (u16*)d_ws;
  float*  s1g  = (float*)((char*)d_ws + WHTF_B);
  float2* bdg  = (float2*)((char*)d_ws + WHTF_B + S1_B);
  unsigned* Abits = (ws_size >= AB_OFF + ABITS_B)
                  ? (unsigned*)((char*)d_ws + AB_OFF)
                  : (unsigned*)((char*)d_out + 2097152);
  u16* Wf = (u16*)d_out;   // k_ab -> k1 -> k2 serialize; k2 overwrites d_out last

  hipLaunchKernelGGL(k_ab, dim3(2048), dim3(256), 0, stream, A, Abits, W, Wf);
  hipLaunchKernelGGL(k1_wh, dim3(L_ / 16 * 4), dim3(256), 0, stream,
                     h, Wf, attn, WhTf, s1g, bdg);
  hipLaunchKernelGGL(k2_attn, dim3(L_ / 16), dim3(1024), 0, stream,
                     Abits, WhTf, s1g, bdg, out_w, out_b, outp);
}